// Round 16
// baseline (278.129 us; speedup 1.0000x reference)
//
#include <hip/hip_runtime.h>

// ---------------------------------------------------------------------------
// SLAYER SNN on MI355X — layer 1 on i8 MATRIX CORES, exact integer limbs.
//   q[o,f] = rint(W1[o,f]*2^27) == l0 + 256 l1 + 65536 l2 + 2^24 l3 (signed
//   i8 limbs, exact). z*2^27 = sum_l 2^(8l) * (limb_l GEMM x), x in {0,1},
//   v_mfma_i32_32x32x32_i8 (exact). M limb-interleaved (m=o*4+l) -> limbs
//   combine in-register (wrapping u32, exact since |s| < 2^31); 8 i32 kc
//   planes sum exactly in i64 in redpsp1. z integer-identical throughout.
// Round 16: layers 2/3 sparse GEMMs FUSED into their redpsp kernels — each
// thread (one column t) walks its register-resident input bitmask and
// gathers QT[f][og*16..+15] (L1-resident 26KB slice), accumulating 16 i32
// regs in ascending-f order = identical exact sums. Kills sparse_gemm
// launches, z buffers, LDS list machinery. 5 launches (was 7).
// ---------------------------------------------------------------------------

#define B   8
#define T   300
#define F0  16384
#define O1  410
#define O2  240
#define OP2 240
#define O3  10
#define OP3 16
#define NCOLS (B*T)       // 2400
#define PPLC32 ((size_t)416 * NCOLS)   // i32 elements per kc plane

typedef int  int32x4  __attribute__((ext_vector_type(4)));
typedef int  int32x16 __attribute__((ext_vector_type(16)));

// 16 bits -> 16 bytes (0/1): byte i = bit i. Exactly the fragment pattern.
__device__ __forceinline__ int32x4 expand16(unsigned m)
{
    int32x4 r;
    r.x = (int)((((m      ) & 15u) * 0x00204081u) & 0x01010101u);
    r.y = (int)((((m >>  4) & 15u) * 0x00204081u) & 0x01010101u);
    r.z = (int)((((m >>  8) & 15u) * 0x00204081u) & 0x01010101u);
    r.w = (int)((((m >> 12) & 15u) * 0x00204081u) & 0x01010101u);
    return r;
}

// ---------------------------------------------------------------------------
// Fused prep: [0,10240) bitpack x; [10240,11904) quant W1 limbs;
// [11904,12304) quant W2/W3.
// ---------------------------------------------------------------------------
__global__ __launch_bounds__(256) void prep_kernel(
    const float* __restrict__ X,  const float* __restrict__ W1,
    const float* __restrict__ W2, const float* __restrict__ W3,
    unsigned short* __restrict__ Bbit, char* __restrict__ Aswz,
    int* __restrict__ Q2T, int* __restrict__ Q3T)
{
    __shared__ float tileT[64][65];
    int bid = blockIdx.x;
    int tid = threadIdx.x;

    if (bid < 10240) {                           // ---- bitpack x ----
        int tt = bid % 5, fb = (bid / 5) % 256, b = bid / 1280;
        int t0 = tt * 64, f0 = fb * 64;
        const float* Xb = X + ((size_t)b * F0 + f0) * T;
        int fl = tid >> 4;
        int tq = (tid & 15) * 4;
        #pragma unroll
        for (int i = 0; i < 4; ++i) {
            int fr = fl + i * 16;
            int t  = t0 + tq;
            float4 v = make_float4(0.f, 0.f, 0.f, 0.f);
            if (t < T) v = *(const float4*)(Xb + (size_t)fr * T + t);
            tileT[tq + 0][fr] = v.x;
            tileT[tq + 1][fr] = v.y;
            tileT[tq + 2][fr] = v.z;
            tileT[tq + 3][fr] = v.w;
        }
        __syncthreads();
        int sub = tid & 3;
        int tl  = tid >> 2;
        unsigned m = 0u;
        #pragma unroll
        for (int j = 0; j < 16; ++j)
            m |= (tileT[tl][sub * 16 + j] != 0.0f ? 1u : 0u) << j;
        int t = t0 + tl;
        if (t < T)
            Bbit[((size_t)(b * 256 + fb) * 320 + t) * 4 + sub] = (unsigned short)m;

    } else if (bid < 11904) {                    // ---- quant W1 limbs ----
        int j = bid - 10240;                     // 0..1663
        int o  = j >> 2;
        int f0 = ((j & 3) * 256 + tid) * 16;

        float w[16];
        if (o < O1) {
            #pragma unroll
            for (int e = 0; e < 16; e += 4)
                *(float4*)&w[e] = *(const float4*)(W1 + (size_t)o * F0 + f0 + e);
        } else {
            #pragma unroll
            for (int e = 0; e < 16; ++e) w[e] = 0.0f;
        }

        unsigned pk[4][4] = {{0,0,0,0},{0,0,0,0},{0,0,0,0},{0,0,0,0}};
        #pragma unroll
        for (int e = 0; e < 16; ++e) {
            int q = (int)__double2ll_rn((double)w[e] * 134217728.0);   // 2^27
            int l0 = (int)(signed char)(q & 255);  q = (q - l0) >> 8;
            int l1 = (int)(signed char)(q & 255);  q = (q - l1) >> 8;
            int l2 = (int)(signed char)(q & 255);  int l3 = (q - l2) >> 8;
            pk[0][e >> 2] |= (unsigned)(l0 & 255) << (8 * (e & 3));
            pk[1][e >> 2] |= (unsigned)(l1 & 255) << (8 * (e & 3));
            pk[2][e >> 2] |= (unsigned)(l2 & 255) << (8 * (e & 3));
            pk[3][e >> 2] |= (unsigned)(l3 & 255) << (8 * (e & 3));
        }

        int kit = f0 >> 6, ks = (f0 >> 5) & 1, hb = (f0 >> 4) & 1;
        #pragma unroll
        for (int l = 0; l < 4; ++l) {
            int m = o * 4 + l;
            int mt = m >> 7, r = m & 127, g = r >> 5, row = r & 31;
            int word = ks * 64 + row + 32 * hb;
            size_t addr = ((size_t)(mt * 256 + kit) * 4 + g) * 2048 + (size_t)word * 16;
            *(int32x4*)(Aswz + addr) =
                (int32x4){(int)pk[l][0], (int)pk[l][1], (int)pk[l][2], (int)pk[l][3]};
        }

    } else {                                     // ---- quant W2/W3 ----
        int idx = (bid - 11904) * 256 + tid;
        const int n1 = O1 * OP2;                 // 98400
        const int n2 = O2 * OP3;                 // 3840
        if (idx < n1) {
            int f = idx / OP2, o = idx - f * OP2;
            Q2T[idx] = (int)__double2ll_rn((double)W2[(size_t)o * O1 + f] * 67108864.0);
        } else if (idx < n1 + n2) {
            int j = idx - n1;
            int f = j / OP3, o = j - f * OP3;
            double v = (o < O3) ? (double)W3[(size_t)o * O2 + f] : 0.0;
            Q3T[j] = (int)__double2ll_rn(v * 67108864.0);
        }
    }
}

// ---------------------------------------------------------------------------
// LDS-free i8 MFMA GEMM, copy-free 2-stage pipeline, kc=8 (round-15 proven).
// ---------------------------------------------------------------------------
__global__ __launch_bounds__(256) void mfma_gemm_kernel(
    const char* __restrict__ Aswz, const unsigned short* __restrict__ Bbit,
    int* __restrict__ Pc)
{
    int id  = blockIdx.x;
    int xcd = id & 7, rr = id >> 3;
    int bh  = rr & 15, gq = rr >> 4;
    int g   = xcd + 8 * gq;                      // 0..103, exact
    int mt = g >> 3, kc = g & 7;
    int b = bh >> 1, half = bh & 1;

    int tid = threadIdx.x;
    int lane = tid & 63, wv = tid >> 6;
    int wm = wv >> 1, wn = wv & 1;
    int ng0 = wn * 3;
    int nfr = wn ? 2 : 3;                        // wave-uniform

    const char* Ab = Aswz + ((size_t)(mt * 256 + kc * 32) * 4 + wm * 2) * 2048
                          + (size_t)lane * 16;
    const char* Bb = (const char*)Bbit + (size_t)(b * 256 + kc * 32) * 320 * 8;
    int hb16 = (lane >> 5) * 16;

    const char* Bf[3];
    #pragma unroll
    for (int fn = 0; fn < 3; ++fn) {
        int colf = (half * 5 + ng0 + fn) * 32 + (lane & 31);
        Bf[fn] = Bb + (size_t)colf * 8;
    }

    int32x16 acc[2][3];
    #pragma unroll
    for (int fm = 0; fm < 2; ++fm)
        #pragma unroll
        for (int fn = 0; fn < 3; ++fn)
            acc[fm][fn] = (int32x16){0,0,0,0,0,0,0,0,0,0,0,0,0,0,0,0};

    int32x4 aA[2][2], aB[2][2];
    uint2   rA[3],    rB[3];

#define LOAD_STAGE(AR, RR, ITN)                                               \
    { const char* Abn_ = Ab + (size_t)(ITN) * 8192;                           \
      AR[0][0] = *(const int32x4*)(Abn_);                                     \
      AR[0][1] = *(const int32x4*)(Abn_ + 1024);                              \
      AR[1][0] = *(const int32x4*)(Abn_ + 2048);                              \
      AR[1][1] = *(const int32x4*)(Abn_ + 3072);                              \
      _Pragma("unroll")                                                       \
      for (int fn_ = 0; fn_ < 3; ++fn_)                                       \
          if (fn_ < nfr)                                                      \
              RR[fn_] = *(const uint2*)(Bf[fn_] + (size_t)(ITN) * 2560); }

#define COMPUTE_STAGE(AR, RR)                                                 \
    { _Pragma("unroll")                                                       \
      for (int ks_ = 0; ks_ < 2; ++ks_)                                       \
          _Pragma("unroll")                                                   \
          for (int fn_ = 0; fn_ < 3; ++fn_)                                   \
              if (fn_ < nfr) {                                                \
                  unsigned mraw_ = ks_ ? RR[fn_].y : RR[fn_].x;               \
                  int32x4 bvv_ = expand16((mraw_ >> hb16) & 0xFFFFu);         \
                  acc[0][fn_] = __builtin_amdgcn_mfma_i32_32x32x32_i8(        \
                      AR[0][ks_], bvv_, acc[0][fn_], 0, 0, 0);                \
                  acc[1][fn_] = __builtin_amdgcn_mfma_i32_32x32x32_i8(        \
                      AR[1][ks_], bvv_, acc[1][fn_], 0, 0, 0);                \
              } }

    LOAD_STAGE(aA, rA, 0);
    for (int it = 0; it < 32; it += 2) {
        LOAD_STAGE(aB, rB, it + 1);              // it+1 <= 31 always
        COMPUTE_STAGE(aA, rA);
        int itn2 = (it + 2 < 32) ? it + 2 : 31;  // last prefetch harmless
        LOAD_STAGE(aA, rA, itn2);
        COMPUTE_STAGE(aB, rB);
    }
#undef LOAD_STAGE
#undef COMPUTE_STAGE

    // In-register limb combine in wrapping u32 (exact: |s| < 2^31) -> i32.
    int col = lane & 31, h = lane >> 5;
    int* Pk = Pc + (size_t)kc * PPLC32 + (size_t)b * T;
    #pragma unroll
    for (int fm = 0; fm < 2; ++fm) {
        #pragma unroll
        for (int fn = 0; fn < 3; ++fn) {
            if (fn >= nfr) continue;
            int t = (half * 5 + ng0 + fn) * 32 + col;
            if (t >= T) continue;
            int obase = mt * 32 + wm * 16 + fm * 8;
            #pragma unroll
            for (int q = 0; q < 4; ++q) {
                int o = obase + 2 * q + h;
                unsigned s = (unsigned)acc[fm][fn][4 * q]
                           + ((unsigned)acc[fm][fn][4 * q + 1] << 8)
                           + ((unsigned)acc[fm][fn][4 * q + 2] << 16)
                           + ((unsigned)acc[fm][fn][4 * q + 3] << 24);
                Pk[(size_t)o * NCOLS + t] = (int)s;
            }
        }
    }
}

// ---------------------------------------------------------------------------
// Layer 1: sum 8 i32 kc planes in i64 (exact) + psp conv + fused spike LIF.
// smask1: u16[col][28] (== u64[col][7]); slots 26,27 zeroed.
// ---------------------------------------------------------------------------
__global__ __launch_bounds__(320) void redpsp1_kernel(
    const int* __restrict__ Pc, unsigned short* __restrict__ smask)
{
    __shared__ double zs[16][304];
    __shared__ double us[16][304];
    __shared__ double eps[100];
    int og = blockIdx.x, b = blockIdx.y;
    int o0 = og * 16;
    int tid = threadIdx.x;
    const double sc27 = 1.0 / 134217728.0;

    if (tid < 100) {
        double td = (double)tid;
        eps[tid] = (td / 10.0) * exp(1.0 - td / 10.0);
    }
    if (tid < T) {
        size_t col = (size_t)b * T + tid;
        #pragma unroll 4
        for (int ol = 0; ol < 16; ++ol) {
            int o = o0 + ol;
            size_t idx = (size_t)o * NCOLS + col;
            long long s = 0;
            #pragma unroll
            for (int c = 0; c < 8; ++c)
                s += (long long)Pc[(size_t)c * PPLC32 + idx];
            zs[ol][tid] = (double)s * sc27;
        }
    }
    __syncthreads();

    if (tid < T) {
        double sum[16];
        #pragma unroll
        for (int o = 0; o < 16; ++o) sum[o] = 0.0;
        int kmax = tid < 99 ? tid : 99;
        for (int k = 0; k <= kmax; ++k) {
            double e = eps[k];
            #pragma unroll
            for (int o = 0; o < 16; ++o)
                sum[o] = fma(e, zs[o][tid - k], sum[o]);
        }
        #pragma unroll
        for (int o = 0; o < 16; ++o) us[o][tid] = sum[o];
    }
    if (og == 25 && tid < T) {     // zero mask bits 416..447
        size_t col = (size_t)b * T + tid;
        *(unsigned*)((char*)smask + (col * 28 + 26) * 2) = 0u;
    }
    __syncthreads();

    if (tid < 64) {
        int l = tid;
        bool act = (l < 16) && (o0 + l < O1);
        const double alpha = exp(-0.5);
        const double A31   = exp(-15.5);
        const double c0    = -10.0 * exp(1.0);
        double E = 0.0, G = 0.0;
        unsigned hist = 0u;
        for (int t = 0; t < T; ++t) {
            double uval = act ? us[l][t] : -1.0e300;
            double v = uval + c0 * G;
            bool sp = (v >= 10.0);
            unsigned long long bal = __ballot(sp);
            if (l == 0)
                smask[((size_t)b * T + t) * 28 + og] =
                    (unsigned short)(bal & 0xFFFFu);
            double sN  = sp ? 1.0 : 0.0;
            double s31 = ((hist >> 30) & 1u) ? 1.0 : 0.0;
            double Em  = E - A31 * s31;
            double Gm  = G - 31.0 * A31 * s31;
            G = alpha * (sN + Gm + Em);
            E = alpha * (sN + Em);
            hist = (hist << 1) | (sp ? 1u : 0u);
        }
    }
}

// ---------------------------------------------------------------------------
// Layers 2/3 FUSED: per-thread bitmask-gather GEMM (exact i32, ascending f,
// identical sums to the old sparse_gemm) + psp conv + spike.
// FINW: u64 words of input mask/col. NOG output o-groups; SLOTS_OUT u16
// slots (0 = none); OUT: write f32 spikes.
// ---------------------------------------------------------------------------
template<int FINW, int OPAD_, int O_, int NOG, int SLOTS_OUT, bool OUT>
__global__ __launch_bounds__(320) void redpsp_sp_kernel(
    const int* __restrict__ QT, const unsigned long long* __restrict__ inmask,
    unsigned short* __restrict__ omask, float* __restrict__ sout, double scale)
{
    __shared__ double zs[16][304];
    __shared__ double us[16][304];
    __shared__ double eps[100];
    int og = blockIdx.x, b = blockIdx.y;
    int o0 = og * 16;
    int tid = threadIdx.x;

    if (tid < 100) {
        double td = (double)tid;
        eps[tid] = (td / 10.0) * exp(1.0 - td / 10.0);
    }
    if (tid < T) {
        size_t col = (size_t)b * T + tid;
        unsigned long long mw[FINW];
        #pragma unroll
        for (int w = 0; w < FINW; ++w)
            mw[w] = inmask[col * FINW + w];

        int ac[16];
        #pragma unroll
        for (int i = 0; i < 16; ++i) ac[i] = 0;

        #pragma unroll
        for (int w = 0; w < FINW; ++w) {
            unsigned long long m = mw[w];
            while (m) {
                int f = w * 64 + __ffsll(m) - 1;
                m &= m - 1;
                const int* qp = QT + (size_t)f * OPAD_ + o0;
                int4 q0 = *(const int4*)(qp);
                int4 q1 = *(const int4*)(qp + 4);
                int4 q2 = *(const int4*)(qp + 8);
                int4 q3 = *(const int4*)(qp + 12);
                ac[0]  += q0.x; ac[1]  += q0.y; ac[2]  += q0.z; ac[3]  += q0.w;
                ac[4]  += q1.x; ac[5]  += q1.y; ac[6]  += q1.z; ac[7]  += q1.w;
                ac[8]  += q2.x; ac[9]  += q2.y; ac[10] += q2.z; ac[11] += q2.w;
                ac[12] += q3.x; ac[13] += q3.y; ac[14] += q3.z; ac[15] += q3.w;
            }
        }
        #pragma unroll
        for (int ol = 0; ol < 16; ++ol)
            zs[ol][tid] = (double)ac[ol] * scale;
    }
    __syncthreads();

    if (tid < T) {
        double sum[16];
        #pragma unroll
        for (int o = 0; o < 16; ++o) sum[o] = 0.0;
        int kmax = tid < 99 ? tid : 99;
        for (int k = 0; k <= kmax; ++k) {
            double e = eps[k];
            #pragma unroll
            for (int o = 0; o < 16; ++o)
                sum[o] = fma(e, zs[o][tid - k], sum[o]);
        }
        #pragma unroll
        for (int o = 0; o < 16; ++o) us[o][tid] = sum[o];
    }
    if (SLOTS_OUT > NOG && og == NOG - 1 && tid < T) {
        size_t col = (size_t)b * T + tid;
        #pragma unroll
        for (int s = NOG; s < SLOTS_OUT; ++s)
            omask[col * SLOTS_OUT + s] = 0;
    }
    __syncthreads();

    if (tid < 64) {
        int l = tid;
        bool act = (l < 16) && (o0 + l < O_);
        const double alpha = exp(-0.5);
        const double A31   = exp(-15.5);
        const double c0    = -10.0 * exp(1.0);
        double E = 0.0, G = 0.0;
        unsigned hist = 0u;
        for (int t = 0; t < T; ++t) {
            double uval = act ? us[l][t] : -1.0e300;
            double v = uval + c0 * G;
            bool sp = (v >= 10.0);
            unsigned long long bal = __ballot(sp);
            if (SLOTS_OUT > 0 && l == 0)
                omask[((size_t)b * T + t) * SLOTS_OUT + og] =
                    (unsigned short)(bal & 0xFFFFu);
            if (OUT && act)
                sout[((size_t)b * O_ + o0 + l) * T + t] = sp ? 1.0f : 0.0f;
            double sN  = sp ? 1.0 : 0.0;
            double s31 = ((hist >> 30) & 1u) ? 1.0 : 0.0;
            double Em  = E - A31 * s31;
            double Gm  = G - 31.0 * A31 * s31;
            G = alpha * (sN + Gm + Em);
            E = alpha * (sN + Em);
            hist = (hist << 1) | (sp ? 1u : 0u);
        }
    }
}

// ---------------------------------------------------------------------------
extern "C" void kernel_launch(void* const* d_in, const int* in_sizes, int n_in,
                              void* d_out, int out_size, void* d_ws, size_t ws_size,
                              hipStream_t stream)
{
    const float* x  = (const float*)d_in[0];
    const float* W1 = (const float*)d_in[1];
    const float* W2 = (const float*)d_in[2];
    const float* W3 = (const float*)d_in[3];
    float* out = (float*)d_out;

    const size_t sz_Aswz   = (size_t)13 * 256 * 4 * 2048;      // 27.26 MB
    const size_t sz_Bbit   = (size_t)B * 256 * 320 * 4 * 2;    //  5.24 MB
    const size_t sz_Pc     = (size_t)8 * PPLC32 * 4;           // 31.95 MB
    const size_t sz_Q2T    = (size_t)O1 * OP2 * 4;             // 394 KB
    const size_t sz_Q3T    = (size_t)O2 * OP3 * 4;             //  15 KB
    const size_t sz_smask1 = (size_t)NCOLS * 28 * 2;           // 134 KB
    const size_t sz_smask2 = (size_t)NCOLS * 16 * 2;           //  77 KB

    char* p = (char*)d_ws;
    char*           Aswz   = p;                  p += sz_Aswz;
    unsigned short* Bbit   = (unsigned short*)p; p += sz_Bbit;
    int*            Pc     = (int*)p;            p += sz_Pc;
    int*            Q2T    = (int*)p;            p += sz_Q2T;
    int*            Q3T    = (int*)p;            p += sz_Q3T;
    unsigned short* smask1 = (unsigned short*)p; p += sz_smask1;
    unsigned short* smask2 = (unsigned short*)p; p += sz_smask2;

    const double sc26 = 1.0 / 67108864.0;

    // --- prep (fused) ---
    prep_kernel<<<dim3(12304), dim3(256), 0, stream>>>(
        x, W1, W2, W3, Bbit, Aswz, Q2T, Q3T);

    // --- layer 1 (MFMA + fused psp/spike) ---
    mfma_gemm_kernel<<<dim3(1664), dim3(256), 0, stream>>>(Aswz, Bbit, Pc);
    redpsp1_kernel<<<dim3(26, B), dim3(320), 0, stream>>>(Pc, smask1);

    // --- layer 2 (fused sparse-gather + psp + spike) ---
    redpsp_sp_kernel<7, OP2, O2, 15, 16, false><<<dim3(15, B), dim3(320), 0, stream>>>(
        Q2T, (const unsigned long long*)smask1, smask2, (float*)0, sc26);

    // --- layer 3 (fused sparse-gather + psp + spike -> output) ---
    redpsp_sp_kernel<4, OP3, O3, 1, 0, true><<<dim3(1, B), dim3(320), 0, stream>>>(
        Q3T, (const unsigned long long*)smask2, (unsigned short*)0, out, sc26);
}